// Round 10
// baseline (964.326 us; speedup 1.0000x reference)
//
#include <hip/hip_runtime.h>

#define BATCH 4
#define NN 2048
#define MM 2048
#define DIM 128
#define HID 128

typedef __bf16 bf16x8 __attribute__((ext_vector_type(8)));
typedef float f32x16 __attribute__((ext_vector_type(16)));
typedef float f32x4 __attribute__((ext_vector_type(4)));
typedef float f32x2 __attribute__((ext_vector_type(2)));
typedef unsigned short ushort_t;
typedef ushort_t ushort8 __attribute__((ext_vector_type(8)));
typedef unsigned int uint_t;

#define LOG2E 1.44269504088896340736f
#define LN2   0.69314718055994530942f

__device__ __forceinline__ ushort_t f2bf(float f) {
  uint_t u = __builtin_bit_cast(uint_t, f);
  u += 0x7fffu + ((u >> 16) & 1u);
  return (ushort_t)(u >> 16);
}
__device__ __forceinline__ float bflo(uint_t p) { return __builtin_bit_cast(float, p << 16); }
__device__ __forceinline__ float bfhi(uint_t p) { return __builtin_bit_cast(float, p & 0xffff0000u); }

// ---- pre-kernel: fp32 -> bf16 convert + TILE-MAJOR repack of source_val ----
// Lane-linear layout (round-6 verified): chunk t = ((b*64 + jt)*8 + ks)*64 + c
// with c == consuming LANE: half = c>>5, l5 = c&31; chunk holds
// S[b][jt*32+l5][ks*16+half*8 .. +8] as 8 bf16.
// Main-kernel B-fragment load for fixed (jt,ks) is lane*16B contiguous ->
// one 1KB fully-coalesced wave instruction straight from L2 (Sb is 512KB per
// batch = L2-resident; all 2048 blocks of a batch share it).
__global__ void cvt_repack(const float* __restrict__ src, ushort_t* __restrict__ dst) {
  int t = blockIdx.x * 256 + threadIdx.x;   // 131072 chunks
  int c    = t & 63;
  int ks   = (t >> 6) & 7;
  int jt   = (t >> 9) & 63;
  int b    = t >> 15;
  int half = c >> 5, l5 = c & 31;           // lane-linear: c == lane
  int j    = jt * 32 + l5;
  int d0   = ks * 16 + half * 8;
  const float* s = src + ((size_t)(b * MM + j)) * DIM + d0;
  float4 v0 = *reinterpret_cast<const float4*>(s);
  float4 v1 = *reinterpret_cast<const float4*>(s + 4);
  ushort8 u;
  u[0] = f2bf(v0.x); u[1] = f2bf(v0.y); u[2] = f2bf(v0.z); u[3] = f2bf(v0.w);
  u[4] = f2bf(v1.x); u[5] = f2bf(v1.y); u[6] = f2bf(v1.z); u[7] = f2bf(v1.w);
  *reinterpret_cast<ushort8*>(dst + (size_t)t * 8) = u;
}

// ---- pre-kernel: pack (b_in*log2e, w_out*ln2) as bf16 pair per h ----
__global__ void pbw_kernel(const float* __restrict__ b_in, const float* __restrict__ w_out,
                           uint_t* __restrict__ pbw) {
  int h = threadIdx.x;
  pbw[h] = (uint_t)f2bf(b_in[h] * LOG2E) | ((uint_t)f2bf(w_out[h] * LN2) << 16);
}

// ---------------- main kernel ----------------
// 8192 blocks = one (b,i); 4 waves; wave wv owns h-quarter [32wv,32wv+32).
// ROUND 10 — lean structure × 4-block residency:
//   Occupancy ledger (r4-r9): achieved blocks/CU follows the launch_bounds
//   waves-per-EU arg ((256,3)->3 blk, (256,4)->4-5 blk, unbounded->2 blk at
//   VGPR=100). The two (256,4) spill disasters were FAT kernels needing >128
//   VGPR; THIS barrier-free structure measured 84 VGPR (r8) -> fits the 128
//   cap with margin. LDS 32KB allows 5 blocks. r9 showed the kernel is
//   latency-limited at low residency (VALUBusy rose as occupancy fell), so
//   the extra resident blocks should convert directly to issue utilization.
//   Spill tripwire: WRITE_SIZE must stay exactly 65536 KB.
// Keeps (verified): barrier-free K-loop, direct-from-L2 B reads (lane-linear
// repack, 1KB coalesced), part[4][MM] write-once rows, cinit bias-fold,
// one-time w2 unpack, packed-fp32 epilogue, two-pointer loadB (offset fold).
__launch_bounds__(256, 4)
__global__ void hmlp_kernel(const float* __restrict__ Tg, const ushort_t* __restrict__ Sb,
                            const float* __restrict__ Wg, const uint_t* __restrict__ pbw,
                            const float* __restrict__ b_out_p, float* __restrict__ Og) {
  __shared__ float part[4][MM];   // 32 KB: per-h-quarter output-row partials
  const int tid  = threadIdx.x;
  const int lane = tid & 63;
  const int wv   = tid >> 6;
  const int half = lane >> 5;     // lane half (0/1)
  const int l5   = lane & 31;
  const int blk  = blockIdx.x;
  const int b    = blk >> 11;     // 2048 blocks per batch
  const int i    = blk & 2047;
  const int hb   = wv << 5;       // this wave's h-base (0/32/64/96)

  // one-time unpack: bias' -> MFMA C-in seed, w' -> packed float2 pairs
  // h_r = hb + (r&3) + 8*(r>>2) + 4*half  (C/D row map, verified)
  f32x16 cinit;
  f32x2 w2[8];
#pragma unroll
  for (int r = 0; r < 16; ++r) {
    uint_t pw = pbw[hb + (r & 3) + 8 * (r >> 2) + 4 * half];
    cinit[r] = bflo(pw);
    if (r & 1) w2[r >> 1].y = bfhi(pw); else w2[r >> 1].x = bfhi(pw);
  }

  // ---- A-fragments afr[ks] = bf16(LOG2E * t_i[d] * W[h][d]) ----
  // A row = hb + l5, k(=d) = ks*16 + half*8 + e   (verified)
  bf16x8 afr[8];
  {
    const float* tb = Tg + ((size_t)(b * NN + i)) * DIM;
    const float* wr = Wg + (size_t)(hb + l5) * DIM;
#pragma unroll
    for (int ks = 0; ks < 8; ++ks) {
      const int d0 = ks * 16 + half * 8;
      float4 w0 = *reinterpret_cast<const float4*>(wr + d0);
      float4 w1 = *reinterpret_cast<const float4*>(wr + d0 + 4);
      float4 t0 = *reinterpret_cast<const float4*>(tb + d0);
      float4 t1 = *reinterpret_cast<const float4*>(tb + d0 + 4);
      ushort8 u;
      u[0] = f2bf(w0.x * t0.x * LOG2E); u[1] = f2bf(w0.y * t0.y * LOG2E);
      u[2] = f2bf(w0.z * t0.z * LOG2E); u[3] = f2bf(w0.w * t0.w * LOG2E);
      u[4] = f2bf(w1.x * t1.x * LOG2E); u[5] = f2bf(w1.y * t1.y * LOG2E);
      u[6] = f2bf(w1.z * t1.z * LOG2E); u[7] = f2bf(w1.w * t1.w * LOG2E);
      afr[ks] = __builtin_bit_cast(bf16x8, u);
    }
  }

  // ---- B: direct from global (L2-hot), lane-linear tile-major layout ----
  // Two base pointers so ks-offsets (<=3KB) fold into the 13-bit signed
  // global_load immediate (saves per-jt address VALU).
  const ushort_t* sbT = Sb + (size_t)b * (64 * 4096) + (size_t)lane * 8;

  auto loadB = [&](bf16x8 (&B)[8], int jt) {
    const ushort_t* p0 = sbT + (size_t)jt * 4096;
    const ushort_t* p1 = p0 + 4 * 512;
#pragma unroll
    for (int ks = 0; ks < 4; ++ks) {
      B[ks]     = *reinterpret_cast<const bf16x8*>(p0 + ks * 512);
      B[ks + 4] = *reinterpret_cast<const bf16x8*>(p1 + ks * 512);
    }
  };

  bf16x8 B[8];
  loadB(B, 0);

#pragma unroll 1
  for (int jt = 0; jt < 64; ++jt) {
    // two independent 4-deep chains (ILP 2): k 0..63 / k 64..127
    f32x16 c0 = __builtin_amdgcn_mfma_f32_32x32x16_bf16(afr[0], B[0], cinit, 0, 0, 0);
    f32x16 c1 = __builtin_amdgcn_mfma_f32_32x32x16_bf16(afr[4], B[4], (f32x16)(0.f), 0, 0, 0);
#pragma unroll
    for (int ks = 1; ks < 4; ++ks) {
      c0 = __builtin_amdgcn_mfma_f32_32x32x16_bf16(afr[ks], B[ks], c0, 0, 0, 0);
      c1 = __builtin_amdgcn_mfma_f32_32x32x16_bf16(afr[ks + 4], B[ks + 4], c1, 0, 0, 0);
    }

    // B consumed by the (already-issued) MFMAs -> prefetch next tile into the
    // SAME registers (WAR-safe); the epilogue below covers the L2 latency.
    if (jt + 1 < 64) loadB(B, jt + 1);

    // epilogue (packed fp32): y log2-domain, p += w'*y*sigmoid; per pair:
    // 1 pk_add + 2 exp2 + 1 pk_add + 2 rcp + 1 pk_mul + 1 pk_fma
    f32x2 pc[4] = {f32x2{0.f, 0.f}, f32x2{0.f, 0.f}, f32x2{0.f, 0.f}, f32x2{0.f, 0.f}};
#define EPI_Q(q)                                                                     \
    {                                                                                \
      f32x2 y = __builtin_shufflevector(c0, c0, 2 * (q), 2 * (q) + 1)                \
              + __builtin_shufflevector(c1, c1, 2 * (q), 2 * (q) + 1);               \
      float e0 = __builtin_amdgcn_exp2f(-y.x);                                       \
      float e1 = __builtin_amdgcn_exp2f(-y.y);                                       \
      f32x2 d = f32x2{e0, e1} + 1.0f;                                                \
      f32x2 s = f32x2{__builtin_amdgcn_rcpf(d.x), __builtin_amdgcn_rcpf(d.y)};       \
      f32x2 ys = y * s;                                                              \
      pc[(q) & 3] = __builtin_elementwise_fma(w2[(q)], ys, pc[(q) & 3]);             \
    }
    EPI_Q(0) EPI_Q(1) EPI_Q(2) EPI_Q(3) EPI_Q(4) EPI_Q(5) EPI_Q(6) EPI_Q(7)
#undef EPI_Q
    f32x2 pv = (pc[0] + pc[1]) + (pc[2] + pc[3]);
    float p = pv.x + pv.y;
    p += __shfl_xor(p, 32, 64);                   // combine lane-halves' h-subsets
    if (lane < 32) part[wv][jt * 32 + l5] = p;    // write-once, private row
  }

  __syncthreads();   // the ONLY block-wide sync: part rows complete

  // final: sum 4 h-quarter rows + b_out; contiguous 1KB wave footprints
  {
    const float bo = b_out_p[0];
    const size_t ob = ((size_t)(b * NN + i)) * MM;
#pragma unroll
    for (int k = 0; k < 2; ++k) {
      const int j0 = k * 1024 + tid * 4;
      f32x4 v0 = *reinterpret_cast<const f32x4*>(&part[0][j0]);
      f32x4 v1 = *reinterpret_cast<const f32x4*>(&part[1][j0]);
      f32x4 v2 = *reinterpret_cast<const f32x4*>(&part[2][j0]);
      f32x4 v3 = *reinterpret_cast<const f32x4*>(&part[3][j0]);
      f32x4 o = (v0 + v1) + (v2 + v3);
      o[0] += bo; o[1] += bo; o[2] += bo; o[3] += bo;
      *reinterpret_cast<f32x4*>(&Og[ob + j0]) = o;
    }
  }
}

// ---------------- launch ----------------
extern "C" void kernel_launch(void* const* d_in, const int* in_sizes, int n_in,
                              void* d_out, int out_size, void* d_ws, size_t ws_size,
                              hipStream_t stream) {
  const float* Tg    = (const float*)d_in[0];
  const float* Sg    = (const float*)d_in[1];
  const float* Wg    = (const float*)d_in[2];
  const float* b_in  = (const float*)d_in[3];
  const float* W_out = (const float*)d_in[4];
  const float* b_out = (const float*)d_in[5];
  float* Og = (float*)d_out;

  ushort_t* Sb = (ushort_t*)d_ws;
  uint_t* pbw  = (uint_t*)((char*)d_ws + (size_t)BATCH * MM * DIM * 2);

  cvt_repack<<<(BATCH * MM * DIM) / (256 * 8), 256, 0, stream>>>(Sg, Sb);
  pbw_kernel<<<1, 128, 0, stream>>>(b_in, W_out, pbw);
  hmlp_kernel<<<BATCH * NN, 256, 0, stream>>>(Tg, Sb, Wg, pbw, b_out, Og);
}

// Round 11
// 737.103 us; speedup vs baseline: 1.3083x; 1.3083x over previous
//
#include <hip/hip_runtime.h>

#define BATCH 4
#define NN 2048
#define MM 2048
#define DIM 128
#define HID 128

typedef __bf16 bf16x8 __attribute__((ext_vector_type(8)));
typedef float f32x16 __attribute__((ext_vector_type(16)));
typedef float f32x4 __attribute__((ext_vector_type(4)));
typedef float f32x2 __attribute__((ext_vector_type(2)));
typedef unsigned short ushort_t;
typedef ushort_t ushort8 __attribute__((ext_vector_type(8)));
typedef unsigned int uint_t;

#define LOG2E 1.44269504088896340736f
#define LN2   0.69314718055994530942f

__device__ __forceinline__ ushort_t f2bf(float f) {
  uint_t u = __builtin_bit_cast(uint_t, f);
  u += 0x7fffu + ((u >> 16) & 1u);
  return (ushort_t)(u >> 16);
}
__device__ __forceinline__ float bflo(uint_t p) { return __builtin_bit_cast(float, p << 16); }
__device__ __forceinline__ float bfhi(uint_t p) { return __builtin_bit_cast(float, p & 0xffff0000u); }

// ---- pre-kernel: fp32 -> bf16 convert + TILE-MAJOR repack of source_val ----
// Lane-linear layout (round-6 verified): chunk t = ((b*64 + jt)*8 + ks)*64 + c
// with c == consuming LANE: half = c>>5, l5 = c&31; chunk holds
// S[b][jt*32+l5][ks*16+half*8 .. +8] as 8 bf16. Per-(jt,ks) fragment read is
// lane*16B linear -> conflict-free ds_read_b128; matches global_load_lds's
// uniform-base+lane*16 dest requirement.
__global__ void cvt_repack(const float* __restrict__ src, ushort_t* __restrict__ dst) {
  int t = blockIdx.x * 256 + threadIdx.x;   // 131072 chunks
  int c    = t & 63;
  int ks   = (t >> 6) & 7;
  int jt   = (t >> 9) & 63;
  int b    = t >> 15;
  int half = c >> 5, l5 = c & 31;           // lane-linear: c == lane
  int j    = jt * 32 + l5;
  int d0   = ks * 16 + half * 8;
  const float* s = src + ((size_t)(b * MM + j)) * DIM + d0;
  float4 v0 = *reinterpret_cast<const float4*>(s);
  float4 v1 = *reinterpret_cast<const float4*>(s + 4);
  ushort8 u;
  u[0] = f2bf(v0.x); u[1] = f2bf(v0.y); u[2] = f2bf(v0.z); u[3] = f2bf(v0.w);
  u[4] = f2bf(v1.x); u[5] = f2bf(v1.y); u[6] = f2bf(v1.z); u[7] = f2bf(v1.w);
  *reinterpret_cast<ushort8*>(dst + (size_t)t * 8) = u;
}

// ---- pre-kernel: pack (b_in*log2e, w_out*ln2) as bf16 pair per h ----
__global__ void pbw_kernel(const float* __restrict__ b_in, const float* __restrict__ w_out,
                           uint_t* __restrict__ pbw) {
  int h = threadIdx.x;
  pbw[h] = (uint_t)f2bf(b_in[h] * LOG2E) | ((uint_t)f2bf(w_out[h] * LN2) << 16);
}

// ---------------- main kernel ----------------
// 8192 blocks = one (b,i); 4 waves; wave wv owns h-quarter [32wv,32wv+32).
// ROUND 11 — fit the 128-reg combined (VGPR+AGPR) budget of 4 waves/SIMD:
//   r1/r5/r10 all spilled at (256,4) because live state ~145 > 128 (unified
//   reg file: 512/SIMD / 4 waves). Cuts:
//   * SINGLE MFMA acc chain c (16 regs) instead of c0+c1 (32) -- 8-deep
//     dependent chain; at 4 waves/SIMD other waves fill the MFMA pipe.
//     Bonus: deletes the 8 pk_add(c0+c1)/jt in the epilogue.
//   * part[4][1024] (16KB) flushed TWICE (after jt 31/63) instead of
//     part[4][2048] (32KB) -> LDS total 32KB -> 4 blocks/CU fits 128KB.
//   Estimated live set: afr 32 + B<=24 (JIT ds_reads) + c 16 + cinit 16 +
//   w2 16 + misc ~12 = ~116-124 <= 128.
//   SPILL TRIPWIRE: WRITE_SIZE must be exactly 65536 KB; if not, 4-block is
//   dead -> rerun this kernel at (256,3).
// Keeps (verified): global_load_lds staged B double-buffer (conflict-free,
// lane-linear), cinit bias-fold into MFMA C-in, one-time w2 unpack,
// packed-fp32 epilogue (pk ops + scalar exp2/rcp).
__launch_bounds__(256, 4)
__global__ void hmlp_kernel(const float* __restrict__ Tg, const ushort_t* __restrict__ Sb,
                            const float* __restrict__ Wg, const uint_t* __restrict__ pbw,
                            const float* __restrict__ b_out_p, float* __restrict__ Og) {
  __shared__ float part[4][1024];      // 16 KB: half-row partials (flushed 2x)
  __shared__ ushort_t Bst[2][4096];    // 16 KB: double-buffered 8KB B tile
  const int tid  = threadIdx.x;
  const int lane = tid & 63;
  const int wv   = tid >> 6;
  const int half = lane >> 5;     // lane half (0/1)
  const int l5   = lane & 31;
  const int blk  = blockIdx.x;
  const int b    = blk >> 11;     // 2048 blocks per batch
  const int i    = blk & 2047;
  const int hb   = wv << 5;       // this wave's h-base (0/32/64/96)

  // one-time unpack: bias' -> MFMA C-in seed, w' -> packed float2 pairs
  // h_r = hb + (r&3) + 8*(r>>2) + 4*half  (C/D row map, verified)
  f32x16 cinit;
  f32x2 w2[8];
#pragma unroll
  for (int r = 0; r < 16; ++r) {
    uint_t pw = pbw[hb + (r & 3) + 8 * (r >> 2) + 4 * half];
    cinit[r] = bflo(pw);
    if (r & 1) w2[r >> 1].y = bfhi(pw); else w2[r >> 1].x = bfhi(pw);
  }

  // ---- A-fragments afr[ks] = bf16(LOG2E * t_i[d] * W[h][d]) ----
  // A row = hb + l5, k(=d) = ks*16 + half*8 + e   (verified)
  bf16x8 afr[8];
  {
    const float* tb = Tg + ((size_t)(b * NN + i)) * DIM;
    const float* wr = Wg + (size_t)(hb + l5) * DIM;
#pragma unroll
    for (int ks = 0; ks < 8; ++ks) {
      const int d0 = ks * 16 + half * 8;
      float4 w0 = *reinterpret_cast<const float4*>(wr + d0);
      float4 w1 = *reinterpret_cast<const float4*>(wr + d0 + 4);
      float4 t0 = *reinterpret_cast<const float4*>(tb + d0);
      float4 t1 = *reinterpret_cast<const float4*>(tb + d0 + 4);
      ushort8 u;
      u[0] = f2bf(w0.x * t0.x * LOG2E); u[1] = f2bf(w0.y * t0.y * LOG2E);
      u[2] = f2bf(w0.z * t0.z * LOG2E); u[3] = f2bf(w0.w * t0.w * LOG2E);
      u[4] = f2bf(w1.x * t1.x * LOG2E); u[5] = f2bf(w1.y * t1.y * LOG2E);
      u[6] = f2bf(w1.z * t1.z * LOG2E); u[7] = f2bf(w1.w * t1.w * LOG2E);
      afr[ks] = __builtin_bit_cast(bf16x8, u);
    }
  }

  // ---- B staging: async global->LDS, 16B/lane, 2 instrs per wave per jt ----
  const ushort_t* stage_base = Sb + (size_t)b * (64 * 4096);

  auto stage_async = [&](int jt, int buf) {
    const ushort_t* g0 = stage_base + (size_t)jt * 4096 + wv * 1024 + lane * 8;
    ushort_t* l0 = &Bst[buf][wv * 1024];
    __builtin_amdgcn_global_load_lds(
        (const __attribute__((address_space(1))) uint_t*)(g0),
        (__attribute__((address_space(3))) uint_t*)(l0), 16, 0, 0);
    __builtin_amdgcn_global_load_lds(
        (const __attribute__((address_space(1))) uint_t*)(g0 + 512),
        (__attribute__((address_space(3))) uint_t*)(l0 + 512), 16, 0, 0);
  };

  const float bo = b_out_p[0];
  const size_t ob = ((size_t)(b * NN + i)) * MM;

  // prologue: stage jt=0 into buf 0 (async), barrier drains it
  stage_async(0, 0);
  __syncthreads();

#pragma unroll 1
  for (int jt = 0; jt < 64; ++jt) {
    const int buf = jt & 1;
    if (jt + 1 < 64) stage_async(jt + 1, buf ^ 1);  // async into other buffer

    // ---- compute: SINGLE 8-deep MFMA chain (c seeded with bias via cinit) ----
    const ushort_t* fb = &Bst[buf][lane * 8];
    f32x16 c = __builtin_amdgcn_mfma_f32_32x32x16_bf16(
        afr[0], *reinterpret_cast<const bf16x8*>(fb), cinit, 0, 0, 0);
#pragma unroll
    for (int ks = 1; ks < 8; ++ks)
      c = __builtin_amdgcn_mfma_f32_32x32x16_bf16(
          afr[ks], *reinterpret_cast<const bf16x8*>(fb + ks * 512), c, 0, 0, 0);

    // epilogue (packed fp32): per pair 2 exp2 + 1 pk_add + 2 rcp + 1 pk_mul
    // + 1 pk_fma (bias + K-sum already in c)
    f32x2 pc[4] = {f32x2{0.f, 0.f}, f32x2{0.f, 0.f}, f32x2{0.f, 0.f}, f32x2{0.f, 0.f}};
#define EPI_Q(q)                                                                     \
    {                                                                                \
      f32x2 y = __builtin_shufflevector(c, c, 2 * (q), 2 * (q) + 1);                 \
      float e0 = __builtin_amdgcn_exp2f(-y.x);                                       \
      float e1 = __builtin_amdgcn_exp2f(-y.y);                                       \
      f32x2 d = f32x2{e0, e1} + 1.0f;                                                \
      f32x2 s = f32x2{__builtin_amdgcn_rcpf(d.x), __builtin_amdgcn_rcpf(d.y)};       \
      f32x2 ys = y * s;                                                              \
      pc[(q) & 3] = __builtin_elementwise_fma(w2[(q)], ys, pc[(q) & 3]);             \
    }
    EPI_Q(0) EPI_Q(1) EPI_Q(2) EPI_Q(3) EPI_Q(4) EPI_Q(5) EPI_Q(6) EPI_Q(7)
#undef EPI_Q
    f32x2 pv = (pc[0] + pc[1]) + (pc[2] + pc[3]);
    float p = pv.x + pv.y;
    p += __shfl_xor(p, 32, 64);                       // combine lane-halves' h-subsets
    if (lane < 32) part[wv][(jt & 31) * 32 + l5] = p; // write-once, private row

    __syncthreads();   // buf^1 staged+ready, buf free, part writes visible

    if ((jt & 31) == 31) {
      // ---- flush half-row: sum 4 h-quarters + b_out, contiguous store ----
      const int phase = jt >> 5;                 // 0 or 1
      const int j0 = tid * 4;
      f32x4 v0 = *reinterpret_cast<const f32x4*>(&part[0][j0]);
      f32x4 v1 = *reinterpret_cast<const f32x4*>(&part[1][j0]);
      f32x4 v2 = *reinterpret_cast<const f32x4*>(&part[2][j0]);
      f32x4 v3 = *reinterpret_cast<const f32x4*>(&part[3][j0]);
      f32x4 o = (v0 + v1) + (v2 + v3);
      o[0] += bo; o[1] += bo; o[2] += bo; o[3] += bo;
      *reinterpret_cast<f32x4*>(&Og[ob + phase * 1024 + j0]) = o;
      __syncthreads();   // flush reads done before part is overwritten
    }
  }
}

// ---------------- launch ----------------
extern "C" void kernel_launch(void* const* d_in, const int* in_sizes, int n_in,
                              void* d_out, int out_size, void* d_ws, size_t ws_size,
                              hipStream_t stream) {
  const float* Tg    = (const float*)d_in[0];
  const float* Sg    = (const float*)d_in[1];
  const float* Wg    = (const float*)d_in[2];
  const float* b_in  = (const float*)d_in[3];
  const float* W_out = (const float*)d_in[4];
  const float* b_out = (const float*)d_in[5];
  float* Og = (float*)d_out;

  ushort_t* Sb = (ushort_t*)d_ws;
  uint_t* pbw  = (uint_t*)((char*)d_ws + (size_t)BATCH * MM * DIM * 2);

  cvt_repack<<<(BATCH * MM * DIM) / (256 * 8), 256, 0, stream>>>(Sg, Sb);
  pbw_kernel<<<1, 128, 0, stream>>>(b_in, W_out, pbw);
  hmlp_kernel<<<BATCH * NN, 256, 0, stream>>>(Tg, Sb, Wg, pbw, b_out, Og);
}